// Round 5
// baseline (2542.000 us; speedup 1.0000x reference)
//
#include <hip/hip_runtime.h>
#include <math.h>

#define NB  1024
#define NN  256
#define NF  4
#define NK  3
#define BIG 32
#define HID 2
#define BN_EPS 1e-5f
#define FLT_BIG 3.402823466e38f

typedef float f32x4 __attribute__((ext_vector_type(4)));

static __device__ __forceinline__ f32x4 relu4(f32x4 v) {
    f32x4 z = {0.0f, 0.0f, 0.0f, 0.0f};
    return __builtin_elementwise_max(v, z);
}

// ---------------------------------------------------------------------------
// Kernel 0: zero the BN-stat accumulator (8 doubles in d_ws)
// ---------------------------------------------------------------------------
__global__ void k_zero_ws(double* ws) {
    if (threadIdx.x < 8) ws[threadIdx.x] = 0.0;
}

// ---------------------------------------------------------------------------
// Kernel 1: BatchNorm statistics (fp64 partials -> 8 double atomics)
// ---------------------------------------------------------------------------
__global__ __launch_bounds__(256) void k_bn_reduce(const float4* __restrict__ x,
                                                   double* __restrict__ ws) {
    int tid = blockIdx.x * 256 + threadIdx.x;
    double s[8] = {0, 0, 0, 0, 0, 0, 0, 0};
    for (int r = tid; r < NB * NN; r += 256 * 256) {
        float4 v = x[r];
        s[0] += v.x; s[1] += v.y; s[2] += v.z; s[3] += v.w;
        s[4] += (double)v.x * v.x; s[5] += (double)v.y * v.y;
        s[6] += (double)v.z * v.z; s[7] += (double)v.w * v.w;
    }
#pragma unroll
    for (int off = 32; off > 0; off >>= 1) {
#pragma unroll
        for (int i = 0; i < 8; i++) s[i] += __shfl_down(s[i], off);
    }
    __shared__ double red[4][8];
    int w = threadIdx.x >> 6, lane = threadIdx.x & 63;
    if (lane == 0) {
#pragma unroll
        for (int i = 0; i < 8; i++) red[w][i] = s[i];
    }
    __syncthreads();
    if (threadIdx.x == 0) {
#pragma unroll
        for (int i = 0; i < 8; i++) {
            double t = red[0][i] + red[1][i] + red[2][i] + red[3][i];
            atomicAdd(&ws[i], t);
        }
    }
}

// ---------------------------------------------------------------------------
// Kernel 2: fused BN + encoder conv + decoder conv. One block per graph.
// All register state in f32x4 / scalars with compile-time names (no arrays,
// no 16-wide tuples). Weights in LDS, read as uniform broadcast ds_read_b128.
// kNN path source-identical to the passing round-2 kernel.
// ---------------------------------------------------------------------------

// LDS segment offsets in floats (all 16B-aligned)
#define O_EW1 0       // 256
#define O_EB1 256     // 32
#define O_EW2 288     // 1024
#define O_EB2 1312    // 32
#define O_EW3 1344    // 64
#define O_EB3 1408    // 2 (pad 16)
#define O_DW1 1424    // 128
#define O_DB1 1552    // 32
#define O_DW2 1584    // 1024
#define O_DB2 2608    // 32
#define O_DW3 2640    // 128
#define O_DB3 2768    // 4 (pad)
#define SW_SZ 2784

#define W4(off) (*(const f32x4*)(sw + (off)))

// acc(32 outs as 8 vec4) += s * Wrow[base..base+31]
#define FMA8(sv, base, a0,a1,a2,a3,a4,a5,a6,a7) \
    { float _s = (sv); \
      a0 += _s * W4((base));      a1 += _s * W4((base) + 4);  \
      a2 += _s * W4((base) + 8);  a3 += _s * W4((base) + 12); \
      a4 += _s * W4((base) + 16); a5 += _s * W4((base) + 20); \
      a6 += _s * W4((base) + 24); a7 += _s * W4((base) + 28); }

// acc(16 outs as 4 vec4) += s * Wrow[base..base+15]
#define FMA4(sv, base, a0,a1,a2,a3) \
    { float _t = (sv); \
      a0 += _t * W4((base));     a1 += _t * W4((base) + 4); \
      a2 += _t * W4((base) + 8); a3 += _t * W4((base) + 12); }

// 4 consecutive rows (R..R+3) of a [32][32] weight, inputs from vec4 pv
#define L2ROWS(pv, R, BASE, COFF, q0,q1,q2,q3) \
    FMA4((pv)[0], (BASE) + ((R) + 0) * 32 + (COFF), q0,q1,q2,q3); \
    FMA4((pv)[1], (BASE) + ((R) + 1) * 32 + (COFF), q0,q1,q2,q3); \
    FMA4((pv)[2], (BASE) + ((R) + 2) * 32 + (COFF), q0,q1,q2,q3); \
    FMA4((pv)[3], (BASE) + ((R) + 3) * 32 + (COFF), q0,q1,q2,q3);

// one 16-wide output half of a 32x32 layer, i ascending 0..31
#define L2HALF(BASE, COFF, q0,q1,q2,q3) \
    L2ROWS(p0,  0, BASE, COFF, q0,q1,q2,q3); \
    L2ROWS(p1,  4, BASE, COFF, q0,q1,q2,q3); \
    L2ROWS(p2,  8, BASE, COFF, q0,q1,q2,q3); \
    L2ROWS(p3, 12, BASE, COFF, q0,q1,q2,q3); \
    L2ROWS(p4, 16, BASE, COFF, q0,q1,q2,q3); \
    L2ROWS(p5, 20, BASE, COFF, q0,q1,q2,q3); \
    L2ROWS(p6, 24, BASE, COFF, q0,q1,q2,q3); \
    L2ROWS(p7, 28, BASE, COFF, q0,q1,q2,q3);

// encoder layer3 chunk: rows 2c,2c+1 (ew3 is [32][2] row-major)
#define L3E2(qv, e0, e1, c) \
    { f32x4 _w = W4(O_EW3 + (c) * 4); \
      o0 += (qv)[e0] * _w[0]; o1 += (qv)[e0] * _w[1]; \
      o0 += (qv)[e1] * _w[2]; o1 += (qv)[e1] * _w[3]; }

// decoder layer3 row i (dw3 is [32][4] row-major)
#define L3D(qv, e, i) { ov += (qv)[e] * W4(O_DW3 + (i) * 4); }

__global__ __launch_bounds__(256)
__attribute__((amdgpu_waves_per_eu(2, 4)))
void k_edgenet(
    const float*  __restrict__ x,
    const float*  __restrict__ gmm, const float* __restrict__ bta,
    const float*  __restrict__ ew1, const float* __restrict__ eb1,
    const float*  __restrict__ ew2, const float* __restrict__ eb2,
    const float*  __restrict__ ew3, const float* __restrict__ eb3,
    const float*  __restrict__ dw1, const float* __restrict__ db1,
    const float*  __restrict__ dw2, const float* __restrict__ db2,
    const float*  __restrict__ dw3, const float* __restrict__ db3,
    const double* __restrict__ bnstat,
    float*        __restrict__ out)
{
    __shared__ float4 s_h4[NN];
    __shared__ float  s_sq[NN];
    __shared__ float2 s_he2[NN];
    __shared__ float  s_sq2[NN];
    __shared__ float  sw[SW_SZ] __attribute__((aligned(16)));

    const int n = threadIdx.x;
    const int b = blockIdx.x;

    // ---- cooperative weight staging into LDS ----
    sw[O_EW1 + n] = ew1[n];
    if (n < 32)  sw[O_EB1 + n] = eb1[n];
    for (int i = n; i < 1024; i += 256) sw[O_EW2 + i] = ew2[i];
    if (n < 32)  sw[O_EB2 + n] = eb2[n];
    if (n < 64)  sw[O_EW3 + n] = ew3[n];
    if (n < 2)   sw[O_EB3 + n] = eb3[n];
    if (n < 128) sw[O_DW1 + n] = dw1[n];
    if (n < 32)  sw[O_DB1 + n] = db1[n];
    for (int i = n; i < 1024; i += 256) sw[O_DW2 + i] = dw2[i];
    if (n < 32)  sw[O_DB2 + n] = db2[n];
    if (n < 128) sw[O_DW3 + n] = dw3[n];
    if (n < 4)   sw[O_DB3 + n] = db3[n];

    // ---- BN parameters (uniform, explicit scalars) ----
    const double cnt = (double)(NB * NN);
    double bm0 = bnstat[0] / cnt, bm1 = bnstat[1] / cnt;
    double bm2 = bnstat[2] / cnt, bm3 = bnstat[3] / cnt;
    float mu0 = (float)bm0, mu1 = (float)bm1, mu2 = (float)bm2, mu3 = (float)bm3;
    float rs0 = 1.0f / sqrtf((float)(bnstat[4] / cnt - bm0 * bm0) + BN_EPS);
    float rs1 = 1.0f / sqrtf((float)(bnstat[5] / cnt - bm1 * bm1) + BN_EPS);
    float rs2 = 1.0f / sqrtf((float)(bnstat[6] / cnt - bm2 * bm2) + BN_EPS);
    float rs3 = 1.0f / sqrtf((float)(bnstat[7] / cnt - bm3 * bm3) + BN_EPS);

    float4 xv = ((const float4*)x)[b * NN + n];
    float h0 = (xv.x - mu0) * rs0 * gmm[0] + bta[0];
    float h1 = (xv.y - mu1) * rs1 * gmm[1] + bta[1];
    float h2 = (xv.z - mu2) * rs2 * gmm[2] + bta[2];
    float h3 = (xv.w - mu3) * rs3 * gmm[3] + bta[3];
    s_h4[n] = make_float4(h0, h1, h2, h3);
    float sq = h0 * h0 + h1 * h1 + h2 * h2 + h3 * h3;
    s_sq[n] = sq;
    __syncthreads();

    // ---------------- encoder kNN (source-identical to round 2) ------------
    float d0 = FLT_BIG, d1 = FLT_BIG, d2 = FLT_BIG;
    int   i0 = 0, i1 = 0, i2 = 0;
    for (int m = 0; m < NN; ++m) {
        float4 a = s_h4[m];
        float dot = h0 * a.x + h1 * a.y + h2 * a.z + h3 * a.w;
        float d = (sq + s_sq[m]) - 2.0f * dot;
        bool c0 = d < d0, c1 = d < d1, c2 = d < d2;
        d2 = c1 ? d1 : (c2 ? d : d2);  i2 = c1 ? i1 : (c2 ? m : i2);
        d1 = c0 ? d0 : (c1 ? d : d1);  i1 = c0 ? i0 : (c1 ? m : i1);
        d0 = c0 ? d  : d0;             i0 = c0 ? m  : i0;
    }

    // ---------------- encoder messages + mean ------------------------------
    // hoisted x_i half of layer 1 (rows 0..3, same fmac order)
    f32x4 c0v = W4(O_EB1),      c1v = W4(O_EB1 + 4);
    f32x4 c2v = W4(O_EB1 + 8),  c3v = W4(O_EB1 + 12);
    f32x4 c4v = W4(O_EB1 + 16), c5v = W4(O_EB1 + 20);
    f32x4 c6v = W4(O_EB1 + 24), c7v = W4(O_EB1 + 28);
    FMA8(h0, O_EW1 + 0 * 32, c0v,c1v,c2v,c3v,c4v,c5v,c6v,c7v);
    FMA8(h1, O_EW1 + 1 * 32, c0v,c1v,c2v,c3v,c4v,c5v,c6v,c7v);
    FMA8(h2, O_EW1 + 2 * 32, c0v,c1v,c2v,c3v,c4v,c5v,c6v,c7v);
    FMA8(h3, O_EW1 + 3 * 32, c0v,c1v,c2v,c3v,c4v,c5v,c6v,c7v);

    float ms0 = 0.0f, ms1 = 0.0f;
#pragma unroll 1
    for (int k = 0; k < NK; ++k) {
        int j = (k == 0) ? i0 : ((k == 1) ? i1 : i2);
        f32x4 p0 = c0v, p1 = c1v, p2 = c2v, p3 = c3v;
        f32x4 p4 = c4v, p5 = c5v, p6 = c6v, p7 = c7v;
        if (j != n) {   // delta rows 4..7 (delta==0 when j==n)
            float4 aj = s_h4[j];
            float e4 = aj.x - h0, e5 = aj.y - h1;
            float e6 = aj.z - h2, e7 = aj.w - h3;
            FMA8(e4, O_EW1 + 4 * 32, p0,p1,p2,p3,p4,p5,p6,p7);
            FMA8(e5, O_EW1 + 5 * 32, p0,p1,p2,p3,p4,p5,p6,p7);
            FMA8(e6, O_EW1 + 6 * 32, p0,p1,p2,p3,p4,p5,p6,p7);
            FMA8(e7, O_EW1 + 7 * 32, p0,p1,p2,p3,p4,p5,p6,p7);
        }
        p0 = relu4(p0); p1 = relu4(p1); p2 = relu4(p2); p3 = relu4(p3);
        p4 = relu4(p4); p5 = relu4(p5); p6 = relu4(p6); p7 = relu4(p7);

        // layer 2: [32]->[32] in two 16-output halves (i ascending each)
        f32x4 qa0 = W4(O_EB2),     qa1 = W4(O_EB2 + 4);
        f32x4 qa2 = W4(O_EB2 + 8), qa3 = W4(O_EB2 + 12);
        L2HALF(O_EW2, 0, qa0, qa1, qa2, qa3);
        qa0 = relu4(qa0); qa1 = relu4(qa1); qa2 = relu4(qa2); qa3 = relu4(qa3);

        f32x4 qb0 = W4(O_EB2 + 16), qb1 = W4(O_EB2 + 20);
        f32x4 qb2 = W4(O_EB2 + 24), qb3 = W4(O_EB2 + 28);
        L2HALF(O_EW2, 16, qb0, qb1, qb2, qb3);
        qb0 = relu4(qb0); qb1 = relu4(qb1); qb2 = relu4(qb2); qb3 = relu4(qb3);

        // layer 3: [32]->[2], final relu (i ascending)
        float o0 = sw[O_EB3], o1 = sw[O_EB3 + 1];
        L3E2(qa0, 0, 1, 0);  L3E2(qa0, 2, 3, 1);
        L3E2(qa1, 0, 1, 2);  L3E2(qa1, 2, 3, 3);
        L3E2(qa2, 0, 1, 4);  L3E2(qa2, 2, 3, 5);
        L3E2(qa3, 0, 1, 6);  L3E2(qa3, 2, 3, 7);
        L3E2(qb0, 0, 1, 8);  L3E2(qb0, 2, 3, 9);
        L3E2(qb1, 0, 1, 10); L3E2(qb1, 2, 3, 11);
        L3E2(qb2, 0, 1, 12); L3E2(qb2, 2, 3, 13);
        L3E2(qb3, 0, 1, 14); L3E2(qb3, 2, 3, 15);
        ms0 += fmaxf(o0, 0.0f);
        ms1 += fmaxf(o1, 0.0f);
    }
    float he0 = ms0 / 3.0f, he1 = ms1 / 3.0f;
    s_he2[n] = make_float2(he0, he1);
    float sqe = he0 * he0 + he1 * he1;
    s_sq2[n] = sqe;
    __syncthreads();

    // ---------------- decoder kNN ------------------------------------------
    d0 = FLT_BIG; d1 = FLT_BIG; d2 = FLT_BIG;
    i0 = 0; i1 = 0; i2 = 0;
    for (int m = 0; m < NN; ++m) {
        float2 a = s_he2[m];
        float dot = he0 * a.x + he1 * a.y;
        float d = (sqe + s_sq2[m]) - 2.0f * dot;
        bool c0 = d < d0, c1 = d < d1, c2 = d < d2;
        d2 = c1 ? d1 : (c2 ? d : d2);  i2 = c1 ? i1 : (c2 ? m : i2);
        d1 = c0 ? d0 : (c1 ? d : d1);  i1 = c0 ? i0 : (c1 ? m : i1);
        d0 = c0 ? d  : d0;             i0 = c0 ? m  : i0;
    }

    // ---------------- decoder messages + mean ------------------------------
    // hoisted he_i half of layer 1 (rows 0..1)
    f32x4 g0 = W4(O_DB1),      g1 = W4(O_DB1 + 4);
    f32x4 g2 = W4(O_DB1 + 8),  g3 = W4(O_DB1 + 12);
    f32x4 g4 = W4(O_DB1 + 16), g5 = W4(O_DB1 + 20);
    f32x4 g6 = W4(O_DB1 + 24), g7 = W4(O_DB1 + 28);
    FMA8(he0, O_DW1 + 0 * 32, g0,g1,g2,g3,g4,g5,g6,g7);
    FMA8(he1, O_DW1 + 1 * 32, g0,g1,g2,g3,g4,g5,g6,g7);

    f32x4 osum = {0.0f, 0.0f, 0.0f, 0.0f};
#pragma unroll 1
    for (int k = 0; k < NK; ++k) {
        int j = (k == 0) ? i0 : ((k == 1) ? i1 : i2);
        float2 aj = s_he2[j];
        float e2 = aj.x - he0, e3 = aj.y - he1;

        f32x4 p0 = g0, p1 = g1, p2 = g2, p3 = g3;
        f32x4 p4 = g4, p5 = g5, p6 = g6, p7 = g7;
        FMA8(e2, O_DW1 + 2 * 32, p0,p1,p2,p3,p4,p5,p6,p7);
        FMA8(e3, O_DW1 + 3 * 32, p0,p1,p2,p3,p4,p5,p6,p7);
        p0 = relu4(p0); p1 = relu4(p1); p2 = relu4(p2); p3 = relu4(p3);
        p4 = relu4(p4); p5 = relu4(p5); p6 = relu4(p6); p7 = relu4(p7);

        // layer 2 halves
        f32x4 qa0 = W4(O_DB2),     qa1 = W4(O_DB2 + 4);
        f32x4 qa2 = W4(O_DB2 + 8), qa3 = W4(O_DB2 + 12);
        L2HALF(O_DW2, 0, qa0, qa1, qa2, qa3);
        qa0 = relu4(qa0); qa1 = relu4(qa1); qa2 = relu4(qa2); qa3 = relu4(qa3);

        f32x4 qb0 = W4(O_DB2 + 16), qb1 = W4(O_DB2 + 20);
        f32x4 qb2 = W4(O_DB2 + 24), qb3 = W4(O_DB2 + 28);
        L2HALF(O_DW2, 16, qb0, qb1, qb2, qb3);
        qb0 = relu4(qb0); qb1 = relu4(qb1); qb2 = relu4(qb2); qb3 = relu4(qb3);

        // layer 3: [32]->[4], no final relu (i ascending)
        f32x4 ov = W4(O_DB3);
        L3D(qa0, 0, 0);  L3D(qa0, 1, 1);  L3D(qa0, 2, 2);  L3D(qa0, 3, 3);
        L3D(qa1, 0, 4);  L3D(qa1, 1, 5);  L3D(qa1, 2, 6);  L3D(qa1, 3, 7);
        L3D(qa2, 0, 8);  L3D(qa2, 1, 9);  L3D(qa2, 2, 10); L3D(qa2, 3, 11);
        L3D(qa3, 0, 12); L3D(qa3, 1, 13); L3D(qa3, 2, 14); L3D(qa3, 3, 15);
        L3D(qb0, 0, 16); L3D(qb0, 1, 17); L3D(qb0, 2, 18); L3D(qb0, 3, 19);
        L3D(qb1, 0, 20); L3D(qb1, 1, 21); L3D(qb1, 2, 22); L3D(qb1, 3, 23);
        L3D(qb2, 0, 24); L3D(qb2, 1, 25); L3D(qb2, 2, 26); L3D(qb2, 3, 27);
        L3D(qb3, 0, 28); L3D(qb3, 1, 29); L3D(qb3, 2, 30); L3D(qb3, 3, 31);
        osum += ov;
    }
    float4 o4;
    o4.x = osum[0] / 3.0f; o4.y = osum[1] / 3.0f;
    o4.z = osum[2] / 3.0f; o4.w = osum[3] / 3.0f;
    ((float4*)out)[b * NN + n] = o4;
}

// ---------------------------------------------------------------------------
extern "C" void kernel_launch(void* const* d_in, const int* in_sizes, int n_in,
                              void* d_out, int out_size, void* d_ws, size_t ws_size,
                              hipStream_t stream) {
    const float* x   = (const float*)d_in[0];
    const float* gmm = (const float*)d_in[1];
    const float* bta = (const float*)d_in[2];
    const float* ew1 = (const float*)d_in[3];
    const float* eb1 = (const float*)d_in[4];
    const float* ew2 = (const float*)d_in[5];
    const float* eb2 = (const float*)d_in[6];
    const float* ew3 = (const float*)d_in[7];
    const float* eb3 = (const float*)d_in[8];
    const float* dw1 = (const float*)d_in[9];
    const float* db1 = (const float*)d_in[10];
    const float* dw2 = (const float*)d_in[11];
    const float* db2 = (const float*)d_in[12];
    const float* dw3 = (const float*)d_in[13];
    const float* db3 = (const float*)d_in[14];
    double* ws = (double*)d_ws;
    float* out = (float*)d_out;

    hipLaunchKernelGGL(k_zero_ws, dim3(1), dim3(64), 0, stream, ws);
    hipLaunchKernelGGL(k_bn_reduce, dim3(256), dim3(256), 0, stream,
                       (const float4*)x, ws);
    hipLaunchKernelGGL(k_edgenet, dim3(NB), dim3(256), 0, stream,
                       x, gmm, bta, ew1, eb1, ew2, eb2, ew3, eb3,
                       dw1, db1, dw2, db2, dw3, db3, ws, out);
}

// Round 6
// 307.852 us; speedup vs baseline: 8.2572x; 8.2572x over previous
//
#include <hip/hip_runtime.h>
#include <math.h>

#define NB  1024
#define NN  256
#define NF  4
#define NK  3
#define BIG 32
#define HID 2
#define BN_EPS 1e-5f
#define FLT_BIG 3.402823466e38f

typedef float f32x16 __attribute__((ext_vector_type(16)));

static __device__ __forceinline__ f32x16 splat16(float s) {
    f32x16 v;
#pragma unroll
    for (int k = 0; k < 16; ++k) v[k] = s;
    return v;
}

static __device__ __forceinline__ f32x16 relu16(f32x16 v) {
    return __builtin_elementwise_max(v, splat16(0.0f));
}

static __device__ __forceinline__ f32x16 ldw16(const float* __restrict__ p) {
    // uniform address -> scalarized to s_load_dwordx16 (weights in SGPRs)
    return *(const f32x16*)p;
}

// ---------------------------------------------------------------------------
// Kernel 0: zero the BN-stat accumulator (8 doubles in d_ws)
// ---------------------------------------------------------------------------
__global__ void k_zero_ws(double* ws) {
    if (threadIdx.x < 8) ws[threadIdx.x] = 0.0;
}

// ---------------------------------------------------------------------------
// Kernel 1: BatchNorm statistics (fp64 partials -> 8 double atomics)
// ---------------------------------------------------------------------------
__global__ __launch_bounds__(256) void k_bn_reduce(const float4* __restrict__ x,
                                                   double* __restrict__ ws) {
    int tid = blockIdx.x * 256 + threadIdx.x;
    double s[8] = {0, 0, 0, 0, 0, 0, 0, 0};
    for (int r = tid; r < NB * NN; r += 256 * 256) {
        float4 v = x[r];
        s[0] += v.x; s[1] += v.y; s[2] += v.z; s[3] += v.w;
        s[4] += (double)v.x * v.x; s[5] += (double)v.y * v.y;
        s[6] += (double)v.z * v.z; s[7] += (double)v.w * v.w;
    }
#pragma unroll
    for (int off = 32; off > 0; off >>= 1) {
#pragma unroll
        for (int i = 0; i < 8; i++) s[i] += __shfl_down(s[i], off);
    }
    __shared__ double red[4][8];
    int w = threadIdx.x >> 6, lane = threadIdx.x & 63;
    if (lane == 0) {
#pragma unroll
        for (int i = 0; i < 8; i++) red[w][i] = s[i];
    }
    __syncthreads();
    if (threadIdx.x == 0) {
#pragma unroll
        for (int i = 0; i < 8; i++) {
            double t = red[0][i] + red[1][i] + red[2][i] + red[3][i];
            atomicAdd(&ws[i], t);
        }
    }
}

// ---------------------------------------------------------------------------
// Kernel 2: fused BN + encoder conv + decoder conv. One block per graph.
// Round-2 structure: weights via uniform GLOBAL f32x16 loads (s_load path),
// hidden state in f32x16 registers. __launch_bounds__(256,2) gives the
// allocator a 256-VGPR budget (no AGPR shuttle). L1 x_i-half hoisted out of
// the k-loop; delta rows skipped when j==n (exact-zero contribution).
// kNN path source-identical to the passing round-2 kernel.
// ---------------------------------------------------------------------------
__global__ __launch_bounds__(256, 2) void k_edgenet(
    const float*  __restrict__ x,
    const float*  __restrict__ gmm, const float* __restrict__ bta,
    const float*  __restrict__ ew1, const float* __restrict__ eb1,
    const float*  __restrict__ ew2, const float* __restrict__ eb2,
    const float*  __restrict__ ew3, const float* __restrict__ eb3,
    const float*  __restrict__ dw1, const float* __restrict__ db1,
    const float*  __restrict__ dw2, const float* __restrict__ db2,
    const float*  __restrict__ dw3, const float* __restrict__ db3,
    const double* __restrict__ bnstat,
    float*        __restrict__ out)
{
    __shared__ float s_h[NN][NF];     // normalized input points
    __shared__ float s_sq[NN];        // |h|^2
    __shared__ float s_he[NN][HID];   // encoder output points
    __shared__ float s_sq2[NN];       // |he|^2

    const int n = threadIdx.x;
    const int b = blockIdx.x;

    // BatchNorm parameters (uniform)
    const double cnt = (double)(NB * NN);
    float mu[NF], rstd[NF];
#pragma unroll
    for (int f = 0; f < NF; f++) {
        double m   = bnstat[f] / cnt;
        double var = bnstat[4 + f] / cnt - m * m;
        mu[f]   = (float)m;
        rstd[f] = 1.0f / sqrtf((float)var + BN_EPS);
    }

    float4 xv = ((const float4*)x)[b * NN + n];
    float h0 = (xv.x - mu[0]) * rstd[0] * gmm[0] + bta[0];
    float h1 = (xv.y - mu[1]) * rstd[1] * gmm[1] + bta[1];
    float h2 = (xv.z - mu[2]) * rstd[2] * gmm[2] + bta[2];
    float h3 = (xv.w - mu[3]) * rstd[3] * gmm[3] + bta[3];
    s_h[n][0] = h0; s_h[n][1] = h1; s_h[n][2] = h2; s_h[n][3] = h3;
    float sq = h0 * h0 + h1 * h1 + h2 * h2 + h3 * h3;
    s_sq[n] = sq;
    __syncthreads();

    // ---------------- encoder kNN (source-identical to round 2) ------------
    float d0 = FLT_BIG, d1 = FLT_BIG, d2 = FLT_BIG;
    int   i0 = 0, i1 = 0, i2 = 0;
    for (int m = 0; m < NN; ++m) {
        float a0 = s_h[m][0], a1 = s_h[m][1], a2 = s_h[m][2], a3 = s_h[m][3];
        float dot = h0 * a0 + h1 * a1 + h2 * a2 + h3 * a3;
        float d = (sq + s_sq[m]) - 2.0f * dot;
        bool c0 = d < d0, c1 = d < d1, c2 = d < d2;
        d2 = c1 ? d1 : (c2 ? d : d2);  i2 = c1 ? i1 : (c2 ? m : i2);
        d1 = c0 ? d0 : (c1 ? d : d1);  i1 = c0 ? i0 : (c1 ? m : i1);
        d0 = c0 ? d  : d0;             i0 = c0 ? m  : i0;
    }

    // ---------------- encoder messages + mean ------------------------------
    // hoisted x_i half of layer 1 (rows 0..3; bias-first, i ascending)
    f32x16 c1a = ldw16(eb1), c1b = ldw16(eb1 + 16);
    {
        float hs[4] = {h0, h1, h2, h3};
#pragma unroll
        for (int i = 0; i < 4; i++) {
            f32x16 s = splat16(hs[i]);
            c1a += s * ldw16(ew1 + i * BIG);
            c1b += s * ldw16(ew1 + i * BIG + 16);
        }
    }
    float ms0 = 0.0f, ms1 = 0.0f;
#pragma unroll 1
    for (int k = 0; k < NK; ++k) {
        int j = (k == 0) ? i0 : ((k == 1) ? i1 : i2);
        // layer 1: delta rows 4..7 (delta==0 exactly when j==n)
        f32x16 h1a = c1a, h1b = c1b;
        if (j != n) {
            float e4 = s_h[j][0] - h0, e5 = s_h[j][1] - h1;
            float e6 = s_h[j][2] - h2, e7 = s_h[j][3] - h3;
            float es[4] = {e4, e5, e6, e7};
#pragma unroll
            for (int i = 0; i < 4; i++) {
                f32x16 s = splat16(es[i]);
                h1a += s * ldw16(ew1 + (4 + i) * BIG);
                h1b += s * ldw16(ew1 + (4 + i) * BIG + 16);
            }
        }
        h1a = relu16(h1a); h1b = relu16(h1b);

        // layer 2: [32] -> [32]
        f32x16 h2a = ldw16(eb2), h2b = ldw16(eb2 + 16);
#pragma unroll
        for (int i = 0; i < 16; i++) {
            f32x16 s = splat16(h1a[i]);
            h2a += s * ldw16(ew2 + i * BIG);
            h2b += s * ldw16(ew2 + i * BIG + 16);
        }
#pragma unroll
        for (int i = 0; i < 16; i++) {
            f32x16 s = splat16(h1b[i]);
            h2a += s * ldw16(ew2 + (16 + i) * BIG);
            h2b += s * ldw16(ew2 + (16 + i) * BIG + 16);
        }
        h2a = relu16(h2a); h2b = relu16(h2b);

        // layer 3: [32] -> [2], final relu
        float o0 = eb3[0], o1 = eb3[1];
#pragma unroll
        for (int i = 0; i < 16; i++) {
            o0 += h2a[i] * ew3[i * HID];
            o1 += h2a[i] * ew3[i * HID + 1];
        }
#pragma unroll
        for (int i = 0; i < 16; i++) {
            o0 += h2b[i] * ew3[(16 + i) * HID];
            o1 += h2b[i] * ew3[(16 + i) * HID + 1];
        }
        ms0 += fmaxf(o0, 0.0f);
        ms1 += fmaxf(o1, 0.0f);
    }
    float he0 = ms0 / 3.0f, he1 = ms1 / 3.0f;
    s_he[n][0] = he0; s_he[n][1] = he1;
    float sqe = he0 * he0 + he1 * he1;
    s_sq2[n] = sqe;
    __syncthreads();

    // ---------------- decoder kNN (source-identical to round 2) ------------
    d0 = FLT_BIG; d1 = FLT_BIG; d2 = FLT_BIG;
    i0 = 0; i1 = 0; i2 = 0;
    for (int m = 0; m < NN; ++m) {
        float a0 = s_he[m][0], a1 = s_he[m][1];
        float dot = he0 * a0 + he1 * a1;
        float d = (sqe + s_sq2[m]) - 2.0f * dot;
        bool c0 = d < d0, c1 = d < d1, c2 = d < d2;
        d2 = c1 ? d1 : (c2 ? d : d2);  i2 = c1 ? i1 : (c2 ? m : i2);
        d1 = c0 ? d0 : (c1 ? d : d1);  i1 = c0 ? i0 : (c1 ? m : i1);
        d0 = c0 ? d  : d0;             i0 = c0 ? m  : i0;
    }

    // ---------------- decoder messages + mean ------------------------------
    // hoisted he_i half of layer 1 (rows 0..1)
    f32x16 g1a = ldw16(db1), g1b = ldw16(db1 + 16);
    {
        float hs[2] = {he0, he1};
#pragma unroll
        for (int i = 0; i < 2; i++) {
            f32x16 s = splat16(hs[i]);
            g1a += s * ldw16(dw1 + i * BIG);
            g1b += s * ldw16(dw1 + i * BIG + 16);
        }
    }
    float o0s = 0.0f, o1s = 0.0f, o2s = 0.0f, o3s = 0.0f;
#pragma unroll 1
    for (int k = 0; k < NK; ++k) {
        int j = (k == 0) ? i0 : ((k == 1) ? i1 : i2);
        // layer 1: delta rows 2..3
        f32x16 h1a = g1a, h1b = g1b;
        if (j != n) {
            float e2 = s_he[j][0] - he0, e3 = s_he[j][1] - he1;
            f32x16 s = splat16(e2);
            h1a += s * ldw16(dw1 + 2 * BIG);
            h1b += s * ldw16(dw1 + 2 * BIG + 16);
            s = splat16(e3);
            h1a += s * ldw16(dw1 + 3 * BIG);
            h1b += s * ldw16(dw1 + 3 * BIG + 16);
        }
        h1a = relu16(h1a); h1b = relu16(h1b);

        // layer 2: [32] -> [32]
        f32x16 h2a = ldw16(db2), h2b = ldw16(db2 + 16);
#pragma unroll
        for (int i = 0; i < 16; i++) {
            f32x16 s = splat16(h1a[i]);
            h2a += s * ldw16(dw2 + i * BIG);
            h2b += s * ldw16(dw2 + i * BIG + 16);
        }
#pragma unroll
        for (int i = 0; i < 16; i++) {
            f32x16 s = splat16(h1b[i]);
            h2a += s * ldw16(dw2 + (16 + i) * BIG);
            h2b += s * ldw16(dw2 + (16 + i) * BIG + 16);
        }
        h2a = relu16(h2a); h2b = relu16(h2b);

        // layer 3: [32] -> [4], no final relu
        float o0 = db3[0], o1 = db3[1], o2 = db3[2], o3 = db3[3];
#pragma unroll
        for (int i = 0; i < 16; i++) {
            float s = h2a[i];
            o0 += s * dw3[i * NF];
            o1 += s * dw3[i * NF + 1];
            o2 += s * dw3[i * NF + 2];
            o3 += s * dw3[i * NF + 3];
        }
#pragma unroll
        for (int i = 0; i < 16; i++) {
            float s = h2b[i];
            o0 += s * dw3[(16 + i) * NF];
            o1 += s * dw3[(16 + i) * NF + 1];
            o2 += s * dw3[(16 + i) * NF + 2];
            o3 += s * dw3[(16 + i) * NF + 3];
        }
        o0s += o0; o1s += o1; o2s += o2; o3s += o3;
    }
    float4 ov;
    ov.x = o0s / 3.0f; ov.y = o1s / 3.0f;
    ov.z = o2s / 3.0f; ov.w = o3s / 3.0f;
    ((float4*)out)[b * NN + n] = ov;
}

// ---------------------------------------------------------------------------
extern "C" void kernel_launch(void* const* d_in, const int* in_sizes, int n_in,
                              void* d_out, int out_size, void* d_ws, size_t ws_size,
                              hipStream_t stream) {
    const float* x   = (const float*)d_in[0];
    const float* gmm = (const float*)d_in[1];
    const float* bta = (const float*)d_in[2];
    const float* ew1 = (const float*)d_in[3];
    const float* eb1 = (const float*)d_in[4];
    const float* ew2 = (const float*)d_in[5];
    const float* eb2 = (const float*)d_in[6];
    const float* ew3 = (const float*)d_in[7];
    const float* eb3 = (const float*)d_in[8];
    const float* dw1 = (const float*)d_in[9];
    const float* db1 = (const float*)d_in[10];
    const float* dw2 = (const float*)d_in[11];
    const float* db2 = (const float*)d_in[12];
    const float* dw3 = (const float*)d_in[13];
    const float* db3 = (const float*)d_in[14];
    double* ws = (double*)d_ws;
    float* out = (float*)d_out;

    hipLaunchKernelGGL(k_zero_ws, dim3(1), dim3(64), 0, stream, ws);
    hipLaunchKernelGGL(k_bn_reduce, dim3(256), dim3(256), 0, stream,
                       (const float4*)x, ws);
    hipLaunchKernelGGL(k_edgenet, dim3(NB), dim3(256), 0, stream,
                       x, gmm, bta, ew1, eb1, ew2, eb2, ew3, eb3,
                       dw1, db1, dw2, db2, dw3, db3, ws, out);
}

// Round 8
// 265.572 us; speedup vs baseline: 9.5718x; 1.1592x over previous
//
#include <hip/hip_runtime.h>
#include <math.h>

#define NB  1024
#define NN  256
#define NF  4
#define NK  3
#define BIG 32
#define HID 2
#define BN_EPS 1e-5f
#define FLT_BIG 3.402823466e38f

typedef float f32x16 __attribute__((ext_vector_type(16)));
typedef float f32x4v __attribute__((ext_vector_type(4)));

static __device__ __forceinline__ f32x16 splat16(float s) {
    f32x16 v;
#pragma unroll
    for (int k = 0; k < 16; ++k) v[k] = s;
    return v;
}
static __device__ __forceinline__ f32x16 relu16(f32x16 v) {
    return __builtin_elementwise_max(v, splat16(0.0f));
}
static __device__ __forceinline__ f32x16 ldw16(const float* __restrict__ p) {
    return *(const f32x16*)p;   // uniform addr -> s_load_dwordx16
}
static __device__ __forceinline__ f32x4v ldw4(const float* __restrict__ p) {
    return *(const f32x4v*)p;   // uniform addr -> s_load_dwordx4
}
static __device__ __forceinline__ f32x4v splat4(float s) {
    f32x4v v; v[0] = s; v[1] = s; v[2] = s; v[3] = s; return v;
}

// ---- L1 row into one edge's 32-wide acc pair ----
#define ROW1(s, base, Aa, Ab) { \
    f32x16 w0_ = ldw16(base); f32x16 w1_ = ldw16((base) + 16); \
    f32x16 sv_ = splat16(s); Aa += sv_ * w0_; Ab += sv_ * w1_; }

// ---- L1 row into two edges' acc pairs (row loaded once) ----
#define ROW2(s0, s1, base, A0a, A0b, A1a, A1b) { \
    f32x16 w0_ = ldw16(base); f32x16 w1_ = ldw16((base) + 16); \
    A0a += splat16(s0) * w0_; A0b += splat16(s0) * w1_; \
    A1a += splat16(s1) * w0_; A1b += splat16(s1) * w1_; }

// ---- L2 half (16 outputs at COFF) joint over 2 edges; declares Q0,Q1 ----
#define L2J(wbase, bbase, COFF, IN0a, IN0b, IN1a, IN1b, Q0, Q1) \
    f32x16 Q0 = ldw16((bbase) + (COFF)); f32x16 Q1 = Q0; \
    _Pragma("unroll") \
    for (int i_ = 0; i_ < 16; i_++) { \
        f32x16 w_ = ldw16((wbase) + i_ * BIG + (COFF)); \
        Q0 += splat16(IN0a[i_]) * w_; Q1 += splat16(IN1a[i_]) * w_; } \
    _Pragma("unroll") \
    for (int i_ = 0; i_ < 16; i_++) { \
        f32x16 w_ = ldw16((wbase) + (16 + i_) * BIG + (COFF)); \
        Q0 += splat16(IN0b[i_]) * w_; Q1 += splat16(IN1b[i_]) * w_; } \
    Q0 = relu16(Q0); Q1 = relu16(Q1);

// ---- L2 half solo ----
#define L2S(wbase, bbase, COFF, INa, INb, Q) \
    f32x16 Q = ldw16((bbase) + (COFF)); \
    _Pragma("unroll") \
    for (int i_ = 0; i_ < 16; i_++) { \
        f32x16 w_ = ldw16((wbase) + i_ * BIG + (COFF)); \
        Q += splat16(INa[i_]) * w_; } \
    _Pragma("unroll") \
    for (int i_ = 0; i_ < 16; i_++) { \
        f32x16 w_ = ldw16((wbase) + (16 + i_) * BIG + (COFF)); \
        Q += splat16(INb[i_]) * w_; } \
    Q = relu16(Q);

// ---- encoder L3 partial for a 16-half, joint (ew3 [32][2] row-major) ----
#define L3EJ(COFF, Q0, Q1) { \
    f32x16 wA_ = ldw16(ew3 + (COFF) * 2); \
    f32x16 wB_ = ldw16(ew3 + (COFF) * 2 + 16); \
    _Pragma("unroll") \
    for (int i_ = 0; i_ < 8; i_++) { \
        o0e0 += Q0[i_] * wA_[2 * i_]; o1e0 += Q0[i_] * wA_[2 * i_ + 1]; \
        o0e1 += Q1[i_] * wA_[2 * i_]; o1e1 += Q1[i_] * wA_[2 * i_ + 1]; } \
    _Pragma("unroll") \
    for (int i_ = 0; i_ < 8; i_++) { \
        o0e0 += Q0[8 + i_] * wB_[2 * i_]; o1e0 += Q0[8 + i_] * wB_[2 * i_ + 1]; \
        o0e1 += Q1[8 + i_] * wB_[2 * i_]; o1e1 += Q1[8 + i_] * wB_[2 * i_ + 1]; } }

// ---- encoder L3 partial solo ----
#define L3ES(COFF, Q) { \
    f32x16 wA_ = ldw16(ew3 + (COFF) * 2); \
    f32x16 wB_ = ldw16(ew3 + (COFF) * 2 + 16); \
    _Pragma("unroll") \
    for (int i_ = 0; i_ < 8; i_++) { \
        o0e2 += Q[i_] * wA_[2 * i_]; o1e2 += Q[i_] * wA_[2 * i_ + 1]; } \
    _Pragma("unroll") \
    for (int i_ = 0; i_ < 8; i_++) { \
        o0e2 += Q[8 + i_] * wB_[2 * i_]; o1e2 += Q[8 + i_] * wB_[2 * i_ + 1]; } }

// ---- decoder L3 partial for a 16-half, joint (dw3 [32][4] row-major) ----
#define L3DJ(COFF, Q0, Q1) { \
    _Pragma("unroll") \
    for (int i_ = 0; i_ < 16; i_++) { \
        f32x4v w_ = ldw4(dw3 + ((COFF) + i_) * 4); \
        ove0 += splat4(Q0[i_]) * w_; ove1 += splat4(Q1[i_]) * w_; } }

// ---- decoder L3 partial solo ----
#define L3DS(COFF, Q) { \
    _Pragma("unroll") \
    for (int i_ = 0; i_ < 16; i_++) { \
        f32x4v w_ = ldw4(dw3 + ((COFF) + i_) * 4); \
        ove2 += splat4(Q[i_]) * w_; } }

// ---------------------------------------------------------------------------
__global__ void k_zero_ws(double* ws) {
    if (threadIdx.x < 8) ws[threadIdx.x] = 0.0;
}

__global__ __launch_bounds__(256) void k_bn_reduce(const float4* __restrict__ x,
                                                   double* __restrict__ ws) {
    int tid = blockIdx.x * 256 + threadIdx.x;
    double s[8] = {0, 0, 0, 0, 0, 0, 0, 0};
    for (int r = tid; r < NB * NN; r += 256 * 256) {
        float4 v = x[r];
        s[0] += v.x; s[1] += v.y; s[2] += v.z; s[3] += v.w;
        s[4] += (double)v.x * v.x; s[5] += (double)v.y * v.y;
        s[6] += (double)v.z * v.z; s[7] += (double)v.w * v.w;
    }
#pragma unroll
    for (int off = 32; off > 0; off >>= 1) {
#pragma unroll
        for (int i = 0; i < 8; i++) s[i] += __shfl_down(s[i], off);
    }
    __shared__ double red[4][8];
    int w = threadIdx.x >> 6, lane = threadIdx.x & 63;
    if (lane == 0) {
#pragma unroll
        for (int i = 0; i < 8; i++) red[w][i] = s[i];
    }
    __syncthreads();
    if (threadIdx.x == 0) {
#pragma unroll
        for (int i = 0; i < 8; i++) {
            double t = red[0][i] + red[1][i] + red[2][i] + red[3][i];
            atomicAdd(&ws[i], t);
        }
    }
}

// ---------------------------------------------------------------------------
// Fused kernel. One block per graph. Edges (i0,i1) processed jointly (each
// weight row s_loaded once, fmac'd into both edges' accs), edge i2 solo.
// L2 split into two 16-output half-passes to halve live accumulator state.
// Per-output fmac chains: bias first, input index ascending -> bit-identical
// to the round-2/6 passing numerics. kNN source-identical to round 2.
// ---------------------------------------------------------------------------
__global__ __launch_bounds__(256, 2) void k_edgenet(
    const float*  __restrict__ x,
    const float*  __restrict__ gmm, const float* __restrict__ bta,
    const float*  __restrict__ ew1, const float* __restrict__ eb1,
    const float*  __restrict__ ew2, const float* __restrict__ eb2,
    const float*  __restrict__ ew3, const float* __restrict__ eb3,
    const float*  __restrict__ dw1, const float* __restrict__ db1,
    const float*  __restrict__ dw2, const float* __restrict__ db2,
    const float*  __restrict__ dw3, const float* __restrict__ db3,
    const double* __restrict__ bnstat,
    float*        __restrict__ out)
{
    __shared__ float s_h[NN][NF];
    __shared__ float s_sq[NN];
    __shared__ float s_he[NN][HID];
    __shared__ float s_sq2[NN];

    const int n = threadIdx.x;
    const int b = blockIdx.x;

    // BN parameters (uniform)
    const double cnt = (double)(NB * NN);
    float mu[NF], rstd[NF];
#pragma unroll
    for (int f = 0; f < NF; f++) {
        double m   = bnstat[f] / cnt;
        double var = bnstat[4 + f] / cnt - m * m;
        mu[f]   = (float)m;
        rstd[f] = 1.0f / sqrtf((float)var + BN_EPS);
    }

    float4 xv = ((const float4*)x)[b * NN + n];
    float h0 = (xv.x - mu[0]) * rstd[0] * gmm[0] + bta[0];
    float h1 = (xv.y - mu[1]) * rstd[1] * gmm[1] + bta[1];
    float h2 = (xv.z - mu[2]) * rstd[2] * gmm[2] + bta[2];
    float h3 = (xv.w - mu[3]) * rstd[3] * gmm[3] + bta[3];
    s_h[n][0] = h0; s_h[n][1] = h1; s_h[n][2] = h2; s_h[n][3] = h3;
    float sq = h0 * h0 + h1 * h1 + h2 * h2 + h3 * h3;
    s_sq[n] = sq;
    __syncthreads();

    // ---------------- encoder kNN (source-identical to round 2) ------------
    float d0 = FLT_BIG, d1 = FLT_BIG, d2 = FLT_BIG;
    int   i0 = 0, i1 = 0, i2 = 0;
    for (int m = 0; m < NN; ++m) {
        float a0 = s_h[m][0], a1 = s_h[m][1], a2 = s_h[m][2], a3 = s_h[m][3];
        float dot = h0 * a0 + h1 * a1 + h2 * a2 + h3 * a3;
        float d = (sq + s_sq[m]) - 2.0f * dot;
        bool c0 = d < d0, c1 = d < d1, c2 = d < d2;
        d2 = c1 ? d1 : (c2 ? d : d2);  i2 = c1 ? i1 : (c2 ? m : i2);
        d1 = c0 ? d0 : (c1 ? d : d1);  i1 = c0 ? i0 : (c1 ? m : i1);
        d0 = c0 ? d  : d0;             i0 = c0 ? m  : i0;
    }

    // ---------------- encoder: edges (i0,i1) joint --------------------------
    float ms0, ms1;
    {
        // L1 common rows 0..3 (x_i part), then copy and add per-edge deltas
        f32x16 ca = ldw16(eb1), cb = ldw16(eb1 + 16);
        ROW1(h0, ew1 + 0 * BIG, ca, cb);
        ROW1(h1, ew1 + 1 * BIG, ca, cb);
        ROW1(h2, ew1 + 2 * BIG, ca, cb);
        ROW1(h3, ew1 + 3 * BIG, ca, cb);

        float p00 = s_h[i0][0] - h0, p01 = s_h[i0][1] - h1;
        float p02 = s_h[i0][2] - h2, p03 = s_h[i0][3] - h3;
        float p10 = s_h[i1][0] - h0, p11 = s_h[i1][1] - h1;
        float p12 = s_h[i1][2] - h2, p13 = s_h[i1][3] - h3;

        f32x16 A0a = ca, A0b = cb, A1a = ca, A1b = cb;
        ROW2(p00, p10, ew1 + 4 * BIG, A0a, A0b, A1a, A1b);
        ROW2(p01, p11, ew1 + 5 * BIG, A0a, A0b, A1a, A1b);
        ROW2(p02, p12, ew1 + 6 * BIG, A0a, A0b, A1a, A1b);
        ROW2(p03, p13, ew1 + 7 * BIG, A0a, A0b, A1a, A1b);
        A0a = relu16(A0a); A0b = relu16(A0b);
        A1a = relu16(A1a); A1b = relu16(A1b);

        float o0e0 = eb3[0], o1e0 = eb3[1];
        float o0e1 = eb3[0], o1e1 = eb3[1];
        { L2J(ew2, eb2, 0,  A0a, A0b, A1a, A1b, QA0, QA1); L3EJ(0,  QA0, QA1); }
        { L2J(ew2, eb2, 16, A0a, A0b, A1a, A1b, QB0, QB1); L3EJ(16, QB0, QB1); }
        ms0 = fmaxf(o0e0, 0.0f) + fmaxf(o0e1, 0.0f);
        ms1 = fmaxf(o1e0, 0.0f) + fmaxf(o1e1, 0.0f);
    }
    // ---------------- encoder: edge i2 solo ---------------------------------
    {
        f32x16 Aa = ldw16(eb1), Ab = ldw16(eb1 + 16);
        ROW1(h0, ew1 + 0 * BIG, Aa, Ab);
        ROW1(h1, ew1 + 1 * BIG, Aa, Ab);
        ROW1(h2, ew1 + 2 * BIG, Aa, Ab);
        ROW1(h3, ew1 + 3 * BIG, Aa, Ab);
        float p20 = s_h[i2][0] - h0, p21 = s_h[i2][1] - h1;
        float p22 = s_h[i2][2] - h2, p23 = s_h[i2][3] - h3;
        ROW1(p20, ew1 + 4 * BIG, Aa, Ab);
        ROW1(p21, ew1 + 5 * BIG, Aa, Ab);
        ROW1(p22, ew1 + 6 * BIG, Aa, Ab);
        ROW1(p23, ew1 + 7 * BIG, Aa, Ab);
        Aa = relu16(Aa); Ab = relu16(Ab);

        float o0e2 = eb3[0], o1e2 = eb3[1];
        { L2S(ew2, eb2, 0,  Aa, Ab, QS0); L3ES(0,  QS0); }
        { L2S(ew2, eb2, 16, Aa, Ab, QS1); L3ES(16, QS1); }
        ms0 += fmaxf(o0e2, 0.0f);
        ms1 += fmaxf(o1e2, 0.0f);
    }

    float he0 = ms0 / 3.0f, he1 = ms1 / 3.0f;
    s_he[n][0] = he0; s_he[n][1] = he1;
    float sqe = he0 * he0 + he1 * he1;
    s_sq2[n] = sqe;
    __syncthreads();

    // ---------------- decoder kNN (source-identical to round 2) -------------
    d0 = FLT_BIG; d1 = FLT_BIG; d2 = FLT_BIG;
    i0 = 0; i1 = 0; i2 = 0;
    for (int m = 0; m < NN; ++m) {
        float a0 = s_he[m][0], a1 = s_he[m][1];
        float dot = he0 * a0 + he1 * a1;
        float d = (sqe + s_sq2[m]) - 2.0f * dot;
        bool c0 = d < d0, c1 = d < d1, c2 = d < d2;
        d2 = c1 ? d1 : (c2 ? d : d2);  i2 = c1 ? i1 : (c2 ? m : i2);
        d1 = c0 ? d0 : (c1 ? d : d1);  i1 = c0 ? i0 : (c1 ? m : i1);
        d0 = c0 ? d  : d0;             i0 = c0 ? m  : i0;
    }

    // ---------------- decoder: edges (i0,i1) joint --------------------------
    f32x4v osum;
    {
        f32x16 ca = ldw16(db1), cb = ldw16(db1 + 16);
        ROW1(he0, dw1 + 0 * BIG, ca, cb);
        ROW1(he1, dw1 + 1 * BIG, ca, cb);

        float p00 = s_he[i0][0] - he0, p01 = s_he[i0][1] - he1;
        float p10 = s_he[i1][0] - he0, p11 = s_he[i1][1] - he1;

        f32x16 B0a = ca, B0b = cb, B1a = ca, B1b = cb;
        ROW2(p00, p10, dw1 + 2 * BIG, B0a, B0b, B1a, B1b);
        ROW2(p01, p11, dw1 + 3 * BIG, B0a, B0b, B1a, B1b);
        B0a = relu16(B0a); B0b = relu16(B0b);
        B1a = relu16(B1a); B1b = relu16(B1b);

        f32x4v ove0 = ldw4(db3), ove1 = ldw4(db3);
        { L2J(dw2, db2, 0,  B0a, B0b, B1a, B1b, QD0, QD1); L3DJ(0,  QD0, QD1); }
        { L2J(dw2, db2, 16, B0a, B0b, B1a, B1b, QE0, QE1); L3DJ(16, QE0, QE1); }
        osum = ove0 + ove1;
    }
    // ---------------- decoder: edge i2 solo ---------------------------------
    {
        f32x16 Ba = ldw16(db1), Bb = ldw16(db1 + 16);
        ROW1(he0, dw1 + 0 * BIG, Ba, Bb);
        ROW1(he1, dw1 + 1 * BIG, Ba, Bb);
        float p20 = s_he[i2][0] - he0, p21 = s_he[i2][1] - he1;
        ROW1(p20, dw1 + 2 * BIG, Ba, Bb);
        ROW1(p21, dw1 + 3 * BIG, Ba, Bb);
        Ba = relu16(Ba); Bb = relu16(Bb);

        f32x4v ove2 = ldw4(db3);
        { L2S(dw2, db2, 0,  Ba, Bb, QF0); L3DS(0,  QF0); }
        { L2S(dw2, db2, 16, Ba, Bb, QF1); L3DS(16, QF1); }
        osum += ove2;
    }

    float4 ov;
    ov.x = osum[0] / 3.0f; ov.y = osum[1] / 3.0f;
    ov.z = osum[2] / 3.0f; ov.w = osum[3] / 3.0f;
    ((float4*)out)[b * NN + n] = ov;
}

// ---------------------------------------------------------------------------
extern "C" void kernel_launch(void* const* d_in, const int* in_sizes, int n_in,
                              void* d_out, int out_size, void* d_ws, size_t ws_size,
                              hipStream_t stream) {
    const float* x   = (const float*)d_in[0];
    const float* gmm = (const float*)d_in[1];
    const float* bta = (const float*)d_in[2];
    const float* ew1 = (const float*)d_in[3];
    const float* eb1 = (const float*)d_in[4];
    const float* ew2 = (const float*)d_in[5];
    const float* eb2 = (const float*)d_in[6];
    const float* ew3 = (const float*)d_in[7];
    const float* eb3 = (const float*)d_in[8];
    const float* dw1 = (const float*)d_in[9];
    const float* db1 = (const float*)d_in[10];
    const float* dw2 = (const float*)d_in[11];
    const float* db2 = (const float*)d_in[12];
    const float* dw3 = (const float*)d_in[13];
    const float* db3 = (const float*)d_in[14];
    double* ws = (double*)d_ws;
    float* out = (float*)d_out;

    hipLaunchKernelGGL(k_zero_ws, dim3(1), dim3(64), 0, stream, ws);
    hipLaunchKernelGGL(k_bn_reduce, dim3(256), dim3(256), 0, stream,
                       (const float4*)x, ws);
    hipLaunchKernelGGL(k_edgenet, dim3(NB), dim3(256), 0, stream,
                       x, gmm, bta, ew1, eb1, ew2, eb2, ew3, eb3,
                       dw1, db1, dw2, db2, dw3, db3, ws, out);
}